// Round 3
// baseline (203.663 us; speedup 1.0000x reference)
//
#include <hip/hip_runtime.h>
#include <hip/hip_bf16.h>

#define NROWS 8192
#define DDIM  256
#define INV_TEMP 20.0f   // 1/0.05

typedef __attribute__((ext_vector_type(8))) short bf16x8;
typedef __attribute__((ext_vector_type(4))) float f32x4;

// async global->LDS, 16B per lane. LDS dest = wave-uniform base + lane*16.
__device__ static inline void async16(const void* g, void* l) {
    __builtin_amdgcn_global_load_lds(
        (const __attribute__((address_space(1))) void*)g,
        (__attribute__((address_space(3))) void*)l, 16, 0, 0);
}

// ---------------------------------------------------------------------------
// Kernel 1: per-row L2-normalize q and p (fp32), emit bf16 copies, fp32 diag,
// zero the lse accumulator. 256-thread blocks, one wave per row, 4 rows/block.
// ---------------------------------------------------------------------------
__global__ __launch_bounds__(256) void norm_diag_kernel(
    const float* __restrict__ q, const float* __restrict__ p,
    unsigned short* __restrict__ qn, unsigned short* __restrict__ pn,
    float* __restrict__ diag, float* __restrict__ lse)
{
    const int row  = blockIdx.x * 4 + (threadIdx.x >> 6);
    const int lane = threadIdx.x & 63;

    const float4 qv = ((const float4*)(q + (size_t)row * DDIM))[lane];
    const float4 pv = ((const float4*)(p + (size_t)row * DDIM))[lane];

    float sq = qv.x*qv.x + qv.y*qv.y + qv.z*qv.z + qv.w*qv.w;
    float sp = pv.x*pv.x + pv.y*pv.y + pv.z*pv.z + pv.w*pv.w;
    #pragma unroll
    for (int m = 1; m < 64; m <<= 1) {
        sq += __shfl_xor(sq, m);
        sp += __shfl_xor(sp, m);
    }
    const float qs = 1.0f / fmaxf(sqrtf(sq), 1e-8f);
    const float ps = 1.0f / fmaxf(sqrtf(sp), 1e-8f);

    const float qx = qv.x*qs, qy = qv.y*qs, qz = qv.z*qs, qw = qv.w*qs;
    const float px = pv.x*ps, py = pv.y*ps, pz = pv.z*ps, pw = pv.w*ps;

    float d = qx*px + qy*py + qz*pz + qw*pw;
    #pragma unroll
    for (int m = 1; m < 64; m <<= 1) d += __shfl_xor(d, m);
    if (lane == 0) {
        diag[row] = d * INV_TEMP;
        lse[row]  = 0.0f;          // ws is poisoned each call; simexp atomics need 0
    }

    union { unsigned short u16[4]; uint2 v; } uq, up;
    {
        __hip_bfloat16 b;
        b = __float2bfloat16(qx); uq.u16[0] = *(unsigned short*)&b;
        b = __float2bfloat16(qy); uq.u16[1] = *(unsigned short*)&b;
        b = __float2bfloat16(qz); uq.u16[2] = *(unsigned short*)&b;
        b = __float2bfloat16(qw); uq.u16[3] = *(unsigned short*)&b;
        b = __float2bfloat16(px); up.u16[0] = *(unsigned short*)&b;
        b = __float2bfloat16(py); up.u16[1] = *(unsigned short*)&b;
        b = __float2bfloat16(pz); up.u16[2] = *(unsigned short*)&b;
        b = __float2bfloat16(pw); up.u16[3] = *(unsigned short*)&b;
    }
    *(uint2*)(qn + (size_t)row * DDIM + lane * 4) = uq.v;
    *(uint2*)(pn + (size_t)row * DDIM + lane * 4) = up.v;
}

// ---------------------------------------------------------------------------
// Kernel 2: fused GEMM + sum-exp, double-buffered.
// Block = 256 threads (2x2 waves), tile = 128x128, K = 4 steps of BK=64.
// LDS = 2 buffers x (A 16 KB + B 16 KB) = 64 KB -> 2 blocks/CU.
// One barrier per step; staging of step k+1 issued BEFORE step k's compute,
// so the vmcnt(0) drain at the next barrier has a full step (~32 MFMAs) of
// cover. LDS chunk layout [tile16][khalf][quad][l16]x16B keeps both the
// global_load_lds wave-uniform-dest constraint and linear ds_read_b128 frags.
// Epilogue: exp (|sim|<=20, no max needed), 16-lane shuffle row-sum,
// atomicAdd per row into lse (64 colblocks x few adds -> no contention).
// ---------------------------------------------------------------------------
__global__ __launch_bounds__(256, 2) void simexp_kernel(
    const unsigned short* __restrict__ qn,
    const unsigned short* __restrict__ pn,
    float* __restrict__ lse)
{
    __shared__ unsigned char lds[65536];   // buf b: A @ b*32768, B @ b*32768+16384

    const int tid  = threadIdx.x;
    const int lane = tid & 63;
    const int w    = tid >> 6;        // wave 0..3
    const int wr   = w >> 1;          // wave row (0..1)
    const int wc   = w & 1;           // wave col (0..1)
    const int quad = lane >> 4;
    const int l16  = lane & 15;
    const int rowbase = blockIdx.y * 128;
    const int colbase = blockIdx.x * 128;

    // per-lane global source bases; wave w stages row/col-tiles {2w, 2w+1}
    const unsigned short* sA0 = qn + (size_t)(rowbase + (2*w  )*16 + l16) * DDIM + quad * 8;
    const unsigned short* sA1 = qn + (size_t)(rowbase + (2*w+1)*16 + l16) * DDIM + quad * 8;
    const unsigned short* sB0 = pn + (size_t)(colbase + (2*w  )*16 + l16) * DDIM + quad * 8;
    const unsigned short* sB1 = pn + (size_t)(colbase + (2*w+1)*16 + l16) * DDIM + quad * 8;

    f32x4 acc[4][4];
    #pragma unroll
    for (int i = 0; i < 4; ++i)
        #pragma unroll
        for (int j = 0; j < 4; ++j) acc[i][j] = (f32x4)0.0f;

    // stage BK=64 slice ks into buffer buf: 8 async16 per wave
    #define STAGE(buf, ks)                                                    \
        {                                                                     \
            unsigned char* A_ = lds + (buf) * 32768;                          \
            unsigned char* B_ = A_ + 16384;                                   \
            _Pragma("unroll")                                                 \
            for (int h = 0; h < 2; ++h) {                                     \
                const int off = (ks) * 64 + h * 32;                           \
                async16(sA0 + off, A_ + (4*w     + h) * 1024);                \
                async16(sA1 + off, A_ + (4*w + 2 + h) * 1024);                \
                async16(sB0 + off, B_ + (4*w     + h) * 1024);                \
                async16(sB1 + off, B_ + (4*w + 2 + h) * 1024);                \
            }                                                                 \
        }

    STAGE(0, 0);

    for (int ks = 0; ks < 4; ++ks) {
        __syncthreads();               // staged(ks) visible; buf[ks&1] reads of ks-2 done
        if (ks < 3) STAGE((ks + 1) & 1, ks + 1);

        unsigned char* A = lds + (ks & 1) * 32768;
        unsigned char* B = A + 16384;

        #pragma unroll
        for (int h = 0; h < 2; ++h) {
            bf16x8 af[4], bf[4];
            #pragma unroll
            for (int i = 0; i < 4; ++i)
                af[i] = *(const bf16x8*)(A + ((wr*4 + i)*2 + h) * 1024 + quad * 256 + l16 * 16);
            #pragma unroll
            for (int j = 0; j < 4; ++j)
                bf[j] = *(const bf16x8*)(B + ((wc*4 + j)*2 + h) * 1024 + quad * 256 + l16 * 16);
            #pragma unroll
            for (int i = 0; i < 4; ++i)
                #pragma unroll
                for (int j = 0; j < 4; ++j)
                    acc[i][j] = __builtin_amdgcn_mfma_f32_16x16x32_bf16(
                        af[i], bf[j], acc[i][j], 0, 0, 0);
        }
    }
    #undef STAGE

    // epilogue: per-row sum of exp over this block's 128 cols -> atomicAdd
    #pragma unroll
    for (int i = 0; i < 4; ++i)
        #pragma unroll
        for (int r = 0; r < 4; ++r) {
            float s = __expf(acc[i][0][r] * INV_TEMP)
                    + __expf(acc[i][1][r] * INV_TEMP)
                    + __expf(acc[i][2][r] * INV_TEMP)
                    + __expf(acc[i][3][r] * INV_TEMP);
            s += __shfl_xor(s, 1);
            s += __shfl_xor(s, 2);
            s += __shfl_xor(s, 4);
            s += __shfl_xor(s, 8);
            if (l16 == 0)
                atomicAdd(&lse[rowbase + wr * 64 + i * 16 + quad * 4 + r], s);
        }
}

// ---------------------------------------------------------------------------
// Kernel 3: loss = mean(log(lse) - diag). One 1024-thread block.
// ---------------------------------------------------------------------------
__global__ __launch_bounds__(1024) void final_kernel(
    const float* __restrict__ lse, const float* __restrict__ diag,
    float* __restrict__ out)
{
    float s = 0.0f;
    for (int i = threadIdx.x; i < NROWS; i += 1024)
        s += logf(lse[i]) - diag[i];
    #pragma unroll
    for (int m = 1; m < 64; m <<= 1) s += __shfl_xor(s, m);

    __shared__ float wsum[16];
    if ((threadIdx.x & 63) == 0) wsum[threadIdx.x >> 6] = s;
    __syncthreads();
    if (threadIdx.x < 16) {
        float v = wsum[threadIdx.x];
        #pragma unroll
        for (int m = 1; m < 16; m <<= 1) v += __shfl_xor(v, m);
        if (threadIdx.x == 0) out[0] = v * (1.0f / NROWS);
    }
}

// ---------------------------------------------------------------------------
extern "C" void kernel_launch(void* const* d_in, const int* in_sizes, int n_in,
                              void* d_out, int out_size, void* d_ws, size_t ws_size,
                              hipStream_t stream)
{
    const float* q = (const float*)d_in[0];
    const float* p = (const float*)d_in[1];

    char* ws = (char*)d_ws;
    unsigned short* qn = (unsigned short*)ws;                          // 4 MB
    unsigned short* pn = (unsigned short*)(ws + (size_t)NROWS*DDIM*2); // 4 MB
    float* diag = (float*)(ws + 2 * (size_t)NROWS * DDIM * 2);         // 32 KB
    float* lse  = diag + NROWS;                                        // 32 KB

    norm_diag_kernel<<<NROWS / 4, 256, 0, stream>>>(q, p, qn, pn, diag, lse);

    dim3 grid(64, 64);   // colblocks x rowblocks
    simexp_kernel<<<grid, 256, 0, stream>>>(qn, pn, lse);

    final_kernel<<<1, 1024, 0, stream>>>(lse, diag, (float*)d_out);
}

// Round 4
// 147.289 us; speedup vs baseline: 1.3827x; 1.3827x over previous
//
#include <hip/hip_runtime.h>
#include <hip/hip_bf16.h>

#define NROWS 8192
#define DDIM  256
#define INV_TEMP 20.0f   // 1/0.05

typedef __attribute__((ext_vector_type(8))) short bf16x8;
typedef __attribute__((ext_vector_type(4))) float f32x4;

// async global->LDS, 16B per lane. LDS dest = wave-uniform base + lane*16.
__device__ static inline void async16(const void* g, void* l) {
    __builtin_amdgcn_global_load_lds(
        (const __attribute__((address_space(1))) void*)g,
        (__attribute__((address_space(3))) void*)l, 16, 0, 0);
}

// ---------------------------------------------------------------------------
// Kernel 1: per-row L2-normalize q and p (fp32), emit bf16 copies, fp32 diag,
// zero lse + completion counter. One wave per row, 4 rows per 256-thr block.
// ---------------------------------------------------------------------------
__global__ __launch_bounds__(256) void norm_diag_kernel(
    const float* __restrict__ q, const float* __restrict__ p,
    unsigned short* __restrict__ qn, unsigned short* __restrict__ pn,
    float* __restrict__ diag, float* __restrict__ lse,
    unsigned int* __restrict__ counter)
{
    const int row  = blockIdx.x * 4 + (threadIdx.x >> 6);
    const int lane = threadIdx.x & 63;

    const float4 qv = ((const float4*)(q + (size_t)row * DDIM))[lane];
    const float4 pv = ((const float4*)(p + (size_t)row * DDIM))[lane];

    float sq = qv.x*qv.x + qv.y*qv.y + qv.z*qv.z + qv.w*qv.w;
    float sp = pv.x*pv.x + pv.y*pv.y + pv.z*pv.z + pv.w*pv.w;
    #pragma unroll
    for (int m = 1; m < 64; m <<= 1) {
        sq += __shfl_xor(sq, m);
        sp += __shfl_xor(sp, m);
    }
    const float qs = 1.0f / fmaxf(sqrtf(sq), 1e-8f);
    const float ps = 1.0f / fmaxf(sqrtf(sp), 1e-8f);

    const float qx = qv.x*qs, qy = qv.y*qs, qz = qv.z*qs, qw = qv.w*qs;
    const float px = pv.x*ps, py = pv.y*ps, pz = pv.z*ps, pw = pv.w*ps;

    float d = qx*px + qy*py + qz*pz + qw*pw;
    #pragma unroll
    for (int m = 1; m < 64; m <<= 1) d += __shfl_xor(d, m);
    if (lane == 0) {
        diag[row] = d * INV_TEMP;
        lse[row]  = 0.0f;              // ws is re-poisoned every call
    }
    if (blockIdx.x == 0 && threadIdx.x == 0) *counter = 0u;

    union { unsigned short u16[4]; uint2 v; } uq, up;
    {
        __hip_bfloat16 b;
        b = __float2bfloat16(qx); uq.u16[0] = *(unsigned short*)&b;
        b = __float2bfloat16(qy); uq.u16[1] = *(unsigned short*)&b;
        b = __float2bfloat16(qz); uq.u16[2] = *(unsigned short*)&b;
        b = __float2bfloat16(qw); uq.u16[3] = *(unsigned short*)&b;
        b = __float2bfloat16(px); up.u16[0] = *(unsigned short*)&b;
        b = __float2bfloat16(py); up.u16[1] = *(unsigned short*)&b;
        b = __float2bfloat16(pz); up.u16[2] = *(unsigned short*)&b;
        b = __float2bfloat16(pw); up.u16[3] = *(unsigned short*)&b;
    }
    *(uint2*)(qn + (size_t)row * DDIM + lane * 4) = uq.v;
    *(uint2*)(pn + (size_t)row * DDIM + lane * 4) = up.v;
}

// ---------------------------------------------------------------------------
// Kernel 2: fused GEMM + sum-exp + (last block) final loss.
// Block = 256 thr (4 waves). Each wave owns 32 Q-rows; the full 32x256 A tile
// lives in 64 VGPRs, loaded ONCE (no A staging, no barrier dependence).
// Block covers 128 rows x 1024 cols, processed as 16 chunks of 64 cols.
// Per chunk: stage B (64 P-rows x 512B = 32 KB) into single-buffer LDS with
// the proven 2-barrier pattern, then 64 MFMAs/wave (1024 SIMD-cyc) -- 4x more
// compute per drain than r2. Grid = 512 blocks = exactly 2 per CU, so the
// co-resident block's compute covers this block's vmcnt drain.
// LDS layout [ct(4)][kc(32)][l16(16)]x16B: staging dest is wave-uniform
// (base + lane*16) AND fragment ds_read_b128 is linear (2-way bank = free).
// Epilogue: exp (|sim|<=20.5 -> no max subtraction), 16-lane shuffle rowsum,
// 8 atomicAdd/wave into lse. Last finished block computes the loss.
// ---------------------------------------------------------------------------
__global__ __launch_bounds__(256, 2) void simexp_kernel(
    const unsigned short* __restrict__ qn,
    const unsigned short* __restrict__ pn,
    float* __restrict__ lse, const float* __restrict__ diag,
    unsigned int* __restrict__ counter, float* __restrict__ out)
{
    __shared__ unsigned char lds[32768];
    __shared__ float wsum[4];
    __shared__ unsigned int is_last;

    const int tid  = threadIdx.x;
    const int lane = tid & 63;
    const int w    = tid >> 6;        // wave 0..3
    const int quad = lane >> 4;
    const int l16  = lane & 15;
    const int rowbase  = blockIdx.y * 128;
    const int colstart = blockIdx.x * 1024;
    const int rowstart = rowbase + w * 32;     // this wave's 32 rows

    // --- A tile: 2 row-tiles x 8 k-steps, 64 VGPRs, loaded once ---
    bf16x8 a[2][8];
    #pragma unroll
    for (int rt = 0; rt < 2; ++rt)
        #pragma unroll
        for (int ks = 0; ks < 8; ++ks)
            a[rt][ks] = *(const bf16x8*)(qn +
                (size_t)(rowstart + rt * 16 + l16) * DDIM + ks * 32 + quad * 8);

    // --- B staging source: wave w stages col-tile ct=w of each chunk ---
    const unsigned short* sB = pn +
        (size_t)(colstart + w * 16 + l16) * DDIM + quad * 8;

    float lsum[2][4];
    #pragma unroll
    for (int rt = 0; rt < 2; ++rt)
        #pragma unroll
        for (int r = 0; r < 4; ++r) lsum[rt][r] = 0.0f;

    for (int c = 0; c < 16; ++c) {
        __syncthreads();               // prev chunk's ds_reads complete
        #pragma unroll
        for (int st = 0; st < 8; ++st)
            async16(sB + c * 16384 + st * 32, lds + w * 8192 + st * 1024);
        __syncthreads();               // staging drained (vmcnt(0) + barrier)

        f32x4 acc[2][4];
        #pragma unroll
        for (int rt = 0; rt < 2; ++rt)
            #pragma unroll
            for (int ct = 0; ct < 4; ++ct) acc[rt][ct] = (f32x4)0.0f;

        #pragma unroll
        for (int ks = 0; ks < 8; ++ks) {
            bf16x8 bf[4];
            #pragma unroll
            for (int ct = 0; ct < 4; ++ct)
                bf[ct] = *(const bf16x8*)(lds +
                    ct * 8192 + ks * 1024 + quad * 256 + l16 * 16);
            #pragma unroll
            for (int ct = 0; ct < 4; ++ct)
                #pragma unroll
                for (int rt = 0; rt < 2; ++rt)
                    acc[rt][ct] = __builtin_amdgcn_mfma_f32_16x16x32_bf16(
                        a[rt][ks], bf[ct], acc[rt][ct], 0, 0, 0);
        }

        // accumulate exp(sim) into per-row partials (fp32, no max needed)
        #pragma unroll
        for (int rt = 0; rt < 2; ++rt)
            #pragma unroll
            for (int r = 0; r < 4; ++r)
                lsum[rt][r] += __expf(acc[rt][0][r] * INV_TEMP)
                             + __expf(acc[rt][1][r] * INV_TEMP)
                             + __expf(acc[rt][2][r] * INV_TEMP)
                             + __expf(acc[rt][3][r] * INV_TEMP);
    }

    // row-sum across the 16 col-lanes, one atomicAdd per row
    #pragma unroll
    for (int rt = 0; rt < 2; ++rt)
        #pragma unroll
        for (int r = 0; r < 4; ++r) {
            float s = lsum[rt][r];
            s += __shfl_xor(s, 1);
            s += __shfl_xor(s, 2);
            s += __shfl_xor(s, 4);
            s += __shfl_xor(s, 8);
            if (l16 == 0)
                atomicAdd(&lse[rowstart + rt * 16 + quad * 4 + r], s);
        }

    // --- completion: last block computes the final loss ---
    __threadfence();                   // release our lse contributions
    __syncthreads();
    if (tid == 0) {
        const unsigned int nblk = gridDim.x * gridDim.y;
        is_last = (atomicAdd(counter, 1u) == nblk - 1u);
    }
    __syncthreads();
    if (is_last) {
        __threadfence();               // acquire all blocks' lse atomics
        float s = 0.0f;
        for (int i = tid; i < NROWS; i += 256) {
            float v = __hip_atomic_load(&lse[i], __ATOMIC_RELAXED,
                                        __HIP_MEMORY_SCOPE_AGENT);
            s += __logf(v) - diag[i];
        }
        #pragma unroll
        for (int m = 1; m < 64; m <<= 1) s += __shfl_xor(s, m);
        if (lane == 0) wsum[w] = s;
        __syncthreads();
        if (tid == 0)
            out[0] = (wsum[0] + wsum[1] + wsum[2] + wsum[3]) * (1.0f / NROWS);
    }
}

// ---------------------------------------------------------------------------
extern "C" void kernel_launch(void* const* d_in, const int* in_sizes, int n_in,
                              void* d_out, int out_size, void* d_ws, size_t ws_size,
                              hipStream_t stream)
{
    const float* q = (const float*)d_in[0];
    const float* p = (const float*)d_in[1];

    char* ws = (char*)d_ws;
    unsigned short* qn = (unsigned short*)ws;                          // 4 MB
    unsigned short* pn = (unsigned short*)(ws + (size_t)NROWS*DDIM*2); // 4 MB
    float* diag = (float*)(ws + 2 * (size_t)NROWS * DDIM * 2);         // 32 KB
    float* lse  = diag + NROWS;                                        // 32 KB
    unsigned int* counter = (unsigned int*)(lse + NROWS);              // 4 B

    norm_diag_kernel<<<NROWS / 4, 256, 0, stream>>>(q, p, qn, pn, diag, lse, counter);

    dim3 grid(8, 64);   // colgroups(1024 cols) x rowblocks(128 rows) = 512
    simexp_kernel<<<grid, 256, 0, stream>>>(qn, pn, lse, diag, counter, (float*)d_out);
}